// Round 1
// baseline (1583.568 us; speedup 1.0000x reference)
//
#include <hip/hip_runtime.h>
#include <math.h>

#define B_ 2
#define S_ 2048
#define D_ 4096
#define HQ_ 32
#define HKV_ 8
#define HD_ 128
#define NQKV 6144

typedef __bf16 bf16x8 __attribute__((ext_vector_type(8)));
typedef unsigned short u16x8 __attribute__((ext_vector_type(8)));
typedef float f32x4 __attribute__((ext_vector_type(4)));

__device__ __forceinline__ unsigned short f2bf(float f) {
  unsigned u = __float_as_uint(f);
  u += 0x7FFF + ((u >> 16) & 1);   // round-to-nearest-even
  return (unsigned short)(u >> 16);
}

__device__ __forceinline__ void async16(const void* g, void* l) {
  __builtin_amdgcn_global_load_lds(
      (const __attribute__((address_space(1))) void*)g,
      (__attribute__((address_space(3))) void*)l, 16, 0, 0);
}

// ---------------- fp32 -> bf16 convert ----------------
__global__ void cvt_bf16(const float* __restrict__ src,
                         unsigned short* __restrict__ dst, int n) {
  int stride = gridDim.x * blockDim.x * 4;
  for (int i = (blockIdx.x * blockDim.x + threadIdx.x) * 4; i < n; i += stride) {
    float4 f = *reinterpret_cast<const float4*>(src + i);
    uint2 o;
    o.x = (unsigned)f2bf(f.x) | ((unsigned)f2bf(f.y) << 16);
    o.y = (unsigned)f2bf(f.z) | ((unsigned)f2bf(f.w) << 16);
    *reinterpret_cast<uint2*>(dst + i) = o;
  }
}

// ---------------- GEMM: C[m][n] = sum_k A[m][k] * Bt[n][k], fp32 out ----------------
// m97 structure: 128x128 tile, BK=32, 4 waves each 64x64, global_load_lds width 16.
__global__ __launch_bounds__(256) void gemm_bt(
    const unsigned short* __restrict__ A, const unsigned short* __restrict__ Bt,
    float* __restrict__ C, int M, int N, int K) {
  __shared__ unsigned short As[128 * 32];
  __shared__ unsigned short Bs[128 * 32];
  const int tid = threadIdx.x;
  const int lane = tid & 63;
  const int wave = tid >> 6;
  const int wm = (wave & 1) * 64;
  const int wn = (wave >> 1) * 64;
  const int quad = lane >> 4;
  const int l16 = lane & 15;
  const int bm = blockIdx.x * 128;
  const int bn = blockIdx.y * 128;

  f32x4 acc[4][4] = {};

  const int srow = lane >> 2;        // row within 16-row chunk
  const int scol = (lane & 3) * 8;   // element col within 32

  for (int k0 = 0; k0 < K; k0 += 32) {
#pragma unroll
    for (int t = 0; t < 2; ++t) {
      int c = wave * 2 + t;          // chunk 0..7, 16 rows each
      int row = c * 16 + srow;
      async16(A + (long)(bm + row) * K + k0 + scol, (void*)(As + c * 512));
      async16(Bt + (long)(bn + row) * K + k0 + scol, (void*)(Bs + c * 512));
    }
    __syncthreads();
    bf16x8 af[4], bf[4];
#pragma unroll
    for (int i = 0; i < 4; ++i) {
      af[i] = *reinterpret_cast<const bf16x8*>(As + (wm + i * 16 + l16) * 32 + quad * 8);
      bf[i] = *reinterpret_cast<const bf16x8*>(Bs + (wn + i * 16 + l16) * 32 + quad * 8);
    }
#pragma unroll
    for (int i = 0; i < 4; ++i)
#pragma unroll
      for (int j = 0; j < 4; ++j)
        acc[i][j] = __builtin_amdgcn_mfma_f32_16x16x32_bf16(af[i], bf[j], acc[i][j], 0, 0, 0);
    __syncthreads();
  }
  // epilogue: C/D layout col=lane&15, row=quad*4+reg (m89-verified)
#pragma unroll
  for (int i = 0; i < 4; ++i) {
    int r0 = bm + wm + i * 16 + quad * 4;
#pragma unroll
    for (int j = 0; j < 4; ++j) {
      int col = bn + wn + j * 16 + l16;
#pragma unroll
      for (int r = 0; r < 4; ++r)
        C[(long)(r0 + r) * N + col] = acc[i][j][r];
    }
  }
}

// ---------------- RoPE + repack into head-major bf16 ----------------
// qkv_f: [4096 tokens][6144] fp32. cols 0..4095=q, 4096..5119=k, 5120..6143=v
// q_b: [B][HQ][S][HD] bf16, k_b/v_b: [B][HKV][S][HD] bf16
__global__ void rope_pack(const float* __restrict__ qkv,
                          const float* __restrict__ fc, const float* __restrict__ fs,
                          unsigned short* __restrict__ qb, unsigned short* __restrict__ kb,
                          unsigned short* __restrict__ vb) {
  int pid = blockIdx.x * blockDim.x + threadIdx.x;   // one thread per element pair
  int token = pid / 3072;
  int col = (pid - token * 3072) * 2;
  int b = token >> 11;
  int s = token & 2047;
  float x0 = qkv[(long)token * NQKV + col];
  float x1 = qkv[(long)token * NQKV + col + 1];
  if (col < 4096) {
    int hq = col >> 7, hd = col & 127, j = hd >> 1;
    float c = fc[s * 64 + j], sn = fs[s * 64 + j];
    float y0 = x0 * c - x1 * sn;
    float y1 = x0 * sn + x1 * c;
    unsigned pack = (unsigned)f2bf(y0) | ((unsigned)f2bf(y1) << 16);
    long o = ((long)(b * HQ_ + hq) * S_ + s) * HD_ + hd;
    *reinterpret_cast<unsigned*>(qb + o) = pack;
  } else if (col < 5120) {
    int kc = col - 4096;
    int hk = kc >> 7, hd = kc & 127, j = hd >> 1;
    float c = fc[s * 64 + j], sn = fs[s * 64 + j];
    float y0 = x0 * c - x1 * sn;
    float y1 = x0 * sn + x1 * c;
    unsigned pack = (unsigned)f2bf(y0) | ((unsigned)f2bf(y1) << 16);
    long o = ((long)(b * HKV_ + hk) * S_ + s) * HD_ + hd;
    *reinterpret_cast<unsigned*>(kb + o) = pack;
  } else {
    int vc = col - 5120;
    int hv = vc >> 7, hd = vc & 127;
    unsigned pack = (unsigned)f2bf(x0) | ((unsigned)f2bf(x1) << 16);
    long o = ((long)(b * HKV_ + hv) * S_ + s) * HD_ + hd;
    *reinterpret_cast<unsigned*>(vb + o) = pack;
  }
}

// ---------------- Flash attention (non-causal, T=2048) ----------------
// Grid: (S/128, HQ, B). Block 256 = 4 waves; wave handles 32 q-rows.
// Online softmax state per row; P goes C-layout -> LDS -> A-layout (m120 transform).
__global__ __launch_bounds__(256) void attn(
    const unsigned short* __restrict__ qb, const unsigned short* __restrict__ kb,
    const unsigned short* __restrict__ vb, unsigned short* __restrict__ ob) {
  __shared__ unsigned short Ks[64 * 136];    // 64 keys x 128 hd, +8 pad
  __shared__ unsigned short Vt[128 * 72];    // hd x keys (transposed), +8 pad
  __shared__ unsigned short Ps[4][32 * 72];  // per-wave P 32x64, +8 pad
  const int tid = threadIdx.x;
  const int lane = tid & 63;
  const int wave = tid >> 6;
  const int quad = lane >> 4;
  const int l16 = lane & 15;
  const int qt = blockIdx.x;
  const int h = blockIdx.y;
  const int b = blockIdx.z;
  const int kvh = h >> 2;   // REPEAT = 4
  const unsigned short* qhead = qb + (long)(b * HQ_ + h) * S_ * HD_;
  const unsigned short* khead = kb + (long)(b * HKV_ + kvh) * S_ * HD_;
  const unsigned short* vhead = vb + (long)(b * HKV_ + kvh) * S_ * HD_;
  const int qbase = qt * 128 + wave * 32;

  // Q A-fragments, kept in registers for the whole kernel
  bf16x8 qf[2][4];
#pragma unroll
  for (int mt = 0; mt < 2; ++mt)
#pragma unroll
    for (int kk = 0; kk < 4; ++kk)
      qf[mt][kk] = *reinterpret_cast<const bf16x8*>(
          qhead + (long)(qbase + mt * 16 + l16) * HD_ + kk * 32 + quad * 8);

  f32x4 O[2][8] = {};
  float m_st[2][4], l_st[2][4];
#pragma unroll
  for (int mt = 0; mt < 2; ++mt)
#pragma unroll
    for (int r = 0; r < 4; ++r) { m_st[mt][r] = -INFINITY; l_st[mt][r] = 0.f; }

  const float scale = 0.08838834764831845f;  // 1/sqrt(128)

  for (int t0 = 0; t0 < S_; t0 += 64) {
    __syncthreads();  // protect Ks/Vt from previous iteration's readers
#pragma unroll
    for (int c = tid; c < 1024; c += 256) {  // K tile: 64 rows x 16 chunks
      int row = c >> 4, ch = c & 15;
      *reinterpret_cast<u16x8*>(Ks + row * 136 + ch * 8) =
          *reinterpret_cast<const u16x8*>(khead + (long)(t0 + row) * HD_ + ch * 8);
    }
#pragma unroll
    for (int c = tid; c < 1024; c += 256) {  // V tile, transposed into Vt[hd][key]
      int t = c >> 4, ch = c & 15;
      u16x8 v = *reinterpret_cast<const u16x8*>(vhead + (long)(t0 + t) * HD_ + ch * 8);
#pragma unroll
      for (int j = 0; j < 8; ++j) Vt[(ch * 8 + j) * 72 + t] = v[j];
    }
    __syncthreads();

    // S = Q K^T
    f32x4 sc[2][4] = {};
#pragma unroll
    for (int nt = 0; nt < 4; ++nt) {
#pragma unroll
      for (int kk = 0; kk < 4; ++kk) {
        bf16x8 bk = *reinterpret_cast<const bf16x8*>(Ks + (nt * 16 + l16) * 136 + kk * 32 + quad * 8);
        sc[0][nt] = __builtin_amdgcn_mfma_f32_16x16x32_bf16(qf[0][kk], bk, sc[0][nt], 0, 0, 0);
        sc[1][nt] = __builtin_amdgcn_mfma_f32_16x16x32_bf16(qf[1][kk], bk, sc[1][nt], 0, 0, 0);
      }
    }
#pragma unroll
    for (int mt = 0; mt < 2; ++mt)
#pragma unroll
      for (int nt = 0; nt < 4; ++nt) sc[mt][nt] = sc[mt][nt] * scale;

    // online softmax per row (row = quad*4 + r, replicated over 16 lanes)
#pragma unroll
    for (int mt = 0; mt < 2; ++mt) {
#pragma unroll
      for (int r = 0; r < 4; ++r) {
        float mx = fmaxf(fmaxf(sc[mt][0][r], sc[mt][1][r]), fmaxf(sc[mt][2][r], sc[mt][3][r]));
#pragma unroll
        for (int off = 8; off > 0; off >>= 1) mx = fmaxf(mx, __shfl_xor(mx, off));
        float mnew = fmaxf(m_st[mt][r], mx);
        float al = __expf(m_st[mt][r] - mnew);  // first tile: exp(-inf)=0
        m_st[mt][r] = mnew;
        float rs = 0.f;
#pragma unroll
        for (int nt = 0; nt < 4; ++nt) {
          float p = __expf(sc[mt][nt][r] - mnew);
          sc[mt][nt][r] = p;
          rs += p;
        }
#pragma unroll
        for (int off = 8; off > 0; off >>= 1) rs += __shfl_xor(rs, off);
        l_st[mt][r] = l_st[mt][r] * al + rs;
#pragma unroll
        for (int n = 0; n < 8; ++n) O[mt][n][r] *= al;
      }
    }

    // P: C-layout regs -> per-wave LDS (same-wave RAW, in-order DS pipe)
    unsigned short* pw = Ps[wave];
#pragma unroll
    for (int mt = 0; mt < 2; ++mt)
#pragma unroll
      for (int nt = 0; nt < 4; ++nt)
#pragma unroll
        for (int r = 0; r < 4; ++r)
          pw[(mt * 16 + quad * 4 + r) * 72 + nt * 16 + l16] = f2bf(sc[mt][nt][r]);

    // O += P V
#pragma unroll
    for (int kt = 0; kt < 2; ++kt) {
      bf16x8 ap0 = *reinterpret_cast<const bf16x8*>(pw + (l16) * 72 + kt * 32 + quad * 8);
      bf16x8 ap1 = *reinterpret_cast<const bf16x8*>(pw + (16 + l16) * 72 + kt * 32 + quad * 8);
#pragma unroll
      for (int n = 0; n < 8; ++n) {
        bf16x8 bv = *reinterpret_cast<const bf16x8*>(Vt + (n * 16 + l16) * 72 + kt * 32 + quad * 8);
        O[0][n] = __builtin_amdgcn_mfma_f32_16x16x32_bf16(ap0, bv, O[0][n], 0, 0, 0);
        O[1][n] = __builtin_amdgcn_mfma_f32_16x16x32_bf16(ap1, bv, O[1][n], 0, 0, 0);
      }
    }
  }

  // epilogue: normalize and write attn_b[token][h*128+hd] as bf16
#pragma unroll
  for (int mt = 0; mt < 2; ++mt) {
    float rl[4];
#pragma unroll
    for (int r = 0; r < 4; ++r) rl[r] = 1.f / l_st[mt][r];
#pragma unroll
    for (int n = 0; n < 8; ++n)
#pragma unroll
      for (int r = 0; r < 4; ++r) {
        int srow = qbase + mt * 16 + quad * 4 + r;
        long o = ((long)(b * S_ + srow)) * 4096 + h * HD_ + n * 16 + l16;
        ob[o] = f2bf(O[mt][n][r] * rl[r]);
      }
  }
}

extern "C" void kernel_launch(void* const* d_in, const int* in_sizes, int n_in,
                              void* d_out, int out_size, void* d_ws, size_t ws_size,
                              hipStream_t stream) {
  const float* x  = (const float*)d_in[0];
  const float* wq = (const float*)d_in[1];
  const float* wk = (const float*)d_in[2];
  const float* wv = (const float*)d_in[3];
  const float* wo = (const float*)d_in[4];
  const float* fc = (const float*)d_in[5];
  const float* fs = (const float*)d_in[6];
  // d_in[7]=cache_k, d_in[8]=cache_v (zeros), d_in[9]=start_pos (0) — attention
  // covers the full cache [0,2048) so the cache contents are exactly k,v.

  char* ws = (char*)d_ws;
  unsigned short* x_b    = (unsigned short*)(ws);                 // 33.5 MB
  unsigned short* wqkv_b = (unsigned short*)(ws + 33554432);      // 50.3 MB
  float*          qkv_f  = (float*)(ws + 83886080);               // 100.7 MB
  unsigned short* q_b    = (unsigned short*)(ws + 184549376);     // 33.5 MB
  unsigned short* k_b    = (unsigned short*)(ws + 218103808);     // 8.4 MB
  unsigned short* v_b    = (unsigned short*)(ws + 226492416);     // 8.4 MB -> end 224 MB
  unsigned short* wo_b   = x_b;                      // reuse: x_b dead after gemm1
  unsigned short* attn_b = (unsigned short*)qkv_f;   // reuse: qkv_f dead after rope_pack
  float* out = (float*)d_out;

  cvt_bf16<<<2048, 256, 0, stream>>>(x, x_b, 4096 * 4096);
  cvt_bf16<<<2048, 256, 0, stream>>>(wq, wqkv_b, 4096 * 4096);
  cvt_bf16<<<512, 256, 0, stream>>>(wk, wqkv_b + 4096 * 4096, 1024 * 4096);
  cvt_bf16<<<512, 256, 0, stream>>>(wv, wqkv_b + 5120 * 4096, 1024 * 4096);
  gemm_bt<<<dim3(32, 48), 256, 0, stream>>>(x_b, wqkv_b, qkv_f, 4096, 6144, 4096);
  cvt_bf16<<<2048, 256, 0, stream>>>(wo, wo_b, 4096 * 4096);  // after gemm1 (aliases x_b)
  rope_pack<<<49152, 256, 0, stream>>>(qkv_f, fc, fs, q_b, k_b, v_b);
  attn<<<dim3(16, 32, 2), 256, 0, stream>>>(q_b, k_b, v_b, attn_b);
  gemm_bt<<<dim3(32, 32), 256, 0, stream>>>(attn_b, wo_b, out, 4096, 4096, 4096);
}

// Round 3
// 1103.141 us; speedup vs baseline: 1.4355x; 1.4355x over previous
//
#include <hip/hip_runtime.h>
#include <math.h>

#define B_ 2
#define S_ 2048
#define D_ 4096
#define HQ_ 32
#define HKV_ 8
#define HD_ 128
#define NQKV 6144

typedef __bf16 bf16x8 __attribute__((ext_vector_type(8)));
typedef unsigned short u16x8 __attribute__((ext_vector_type(8)));
typedef float f32x4 __attribute__((ext_vector_type(4)));

__device__ __forceinline__ unsigned short f2bf(float f) {
  unsigned u = __float_as_uint(f);
  u += 0x7FFF + ((u >> 16) & 1);   // round-to-nearest-even
  return (unsigned short)(u >> 16);
}

__device__ __forceinline__ void async16(const void* g, void* l) {
  __builtin_amdgcn_global_load_lds(
      (const __attribute__((address_space(1))) void*)g,
      (__attribute__((address_space(3))) void*)l, 16, 0, 0);
}

// DPP row_ror reductions across the 16-lane DPP row (VALU pipe, no LDS)
template <int CTRL>
__device__ __forceinline__ float dpp_maxf(float x) {
  int y = __builtin_amdgcn_update_dpp(__float_as_int(x), __float_as_int(x),
                                      CTRL, 0xf, 0xf, false);
  return fmaxf(x, __int_as_float(y));
}
template <int CTRL>
__device__ __forceinline__ float dpp_addf(float x) {
  int y = __builtin_amdgcn_update_dpp(__float_as_int(x), __float_as_int(x),
                                      CTRL, 0xf, 0xf, false);
  return x + __int_as_float(y);
}
__device__ __forceinline__ float row_max16(float x) {
  x = dpp_maxf<0x128>(x); x = dpp_maxf<0x124>(x);   // row_ror:8, row_ror:4
  x = dpp_maxf<0x122>(x); x = dpp_maxf<0x121>(x);   // row_ror:2, row_ror:1
  return x;
}
__device__ __forceinline__ float row_sum16(float x) {
  x = dpp_addf<0x128>(x); x = dpp_addf<0x124>(x);
  x = dpp_addf<0x122>(x); x = dpp_addf<0x121>(x);
  return x;
}

// ---------------- fp32 -> bf16 convert ----------------
__global__ void cvt_bf16(const float* __restrict__ src,
                         unsigned short* __restrict__ dst, int n) {
  int stride = gridDim.x * blockDim.x * 4;
  for (int i = (blockIdx.x * blockDim.x + threadIdx.x) * 4; i < n; i += stride) {
    float4 f = *reinterpret_cast<const float4*>(src + i);
    uint2 o;
    o.x = (unsigned)f2bf(f.x) | ((unsigned)f2bf(f.y) << 16);
    o.y = (unsigned)f2bf(f.z) | ((unsigned)f2bf(f.w) << 16);
    *reinterpret_cast<uint2*>(dst + i) = o;
  }
}

// ---------------- GEMM: C[m][n] = sum_k A[m][k] * Bt[n][k] ----------------
// Exact R0/m97 staging (proven correct; fragment reads are bank-balanced:
// slot = 4*(l16&1) + quad covers all 8 slots x 8 lanes).
template <typename OT>
__global__ __launch_bounds__(256) void gemm_bt(
    const unsigned short* __restrict__ A, const unsigned short* __restrict__ Bt,
    OT* __restrict__ C, int M, int N, int K) {
  __shared__ unsigned short As[128 * 32];
  __shared__ unsigned short Bs[128 * 32];
  const int tid = threadIdx.x;
  const int lane = tid & 63;
  const int wave = tid >> 6;
  const int wm = (wave & 1) * 64;
  const int wn = (wave >> 1) * 64;
  const int quad = lane >> 4;
  const int l16 = lane & 15;
  const int bm = blockIdx.x * 128;
  const int bn = blockIdx.y * 128;

  f32x4 acc[4][4] = {};

  const int srow = lane >> 2;        // row within 16-row group
  const int scol = (lane & 3) * 8;   // element col within 32

  for (int k0 = 0; k0 < K; k0 += 32) {
#pragma unroll
    for (int t = 0; t < 2; ++t) {
      int c = wave * 2 + t;          // group 0..7, 16 rows each, 512 shorts
      int row = c * 16 + srow;
      async16(A + (long)(bm + row) * K + k0 + scol, (void*)(As + c * 512));
      async16(Bt + (long)(bn + row) * K + k0 + scol, (void*)(Bs + c * 512));
    }
    __syncthreads();
    bf16x8 af[4], bf[4];
#pragma unroll
    for (int i = 0; i < 4; ++i) {
      af[i] = *reinterpret_cast<const bf16x8*>(As + (wm + i * 16 + l16) * 32 + quad * 8);
      bf[i] = *reinterpret_cast<const bf16x8*>(Bs + (wn + i * 16 + l16) * 32 + quad * 8);
    }
#pragma unroll
    for (int i = 0; i < 4; ++i)
#pragma unroll
      for (int j = 0; j < 4; ++j)
        acc[i][j] = __builtin_amdgcn_mfma_f32_16x16x32_bf16(af[i], bf[j], acc[i][j], 0, 0, 0);
    __syncthreads();
  }
  // epilogue: C/D layout col=lane&15, row=quad*4+reg (m89-verified)
#pragma unroll
  for (int i = 0; i < 4; ++i) {
    int r0 = bm + wm + i * 16 + quad * 4;
#pragma unroll
    for (int j = 0; j < 4; ++j) {
      int col = bn + wn + j * 16 + l16;
#pragma unroll
      for (int r = 0; r < 4; ++r) {
        if constexpr (sizeof(OT) == 2)
          C[(long)(r0 + r) * N + col] = f2bf(acc[i][j][r]);
        else
          C[(long)(r0 + r) * N + col] = acc[i][j][r];
      }
    }
  }
}

// ---------------- RoPE + repack q,k into head-major bf16 ----------------
// qkv_b: [4096 tokens][6144] bf16 (cols 0..4095=q, 4096..5119=k)
// q pre-scaled by 1/sqrt(HD) (folded softmax scale)
__global__ void rope_pack(const unsigned short* __restrict__ qkv,
                          const float* __restrict__ fc, const float* __restrict__ fs,
                          unsigned short* __restrict__ qb, unsigned short* __restrict__ kb) {
  int pid = blockIdx.x * blockDim.x + threadIdx.x;   // one thread per element pair
  int token = pid / 2560;
  int col = (pid - token * 2560) * 2;
  int b = token >> 11;
  int s = token & 2047;
  unsigned v = *reinterpret_cast<const unsigned*>(qkv + (long)token * NQKV + col);
  float x0 = __uint_as_float(v << 16);
  float x1 = __uint_as_float(v & 0xffff0000u);
  int j = (col & 127) >> 1;
  float c = fc[s * 64 + j], sn = fs[s * 64 + j];
  float y0 = x0 * c - x1 * sn;
  float y1 = x0 * sn + x1 * c;
  if (col < 4096) {
    const float qs = 0.08838834764831845f;  // 1/sqrt(128)
    y0 *= qs; y1 *= qs;
    int hq = col >> 7, hd = col & 127;
    long o = ((long)(b * HQ_ + hq) * S_ + s) * HD_ + hd;
    *reinterpret_cast<unsigned*>(qb + o) =
        (unsigned)f2bf(y0) | ((unsigned)f2bf(y1) << 16);
  } else {
    int kc = col - 4096;
    int hk = kc >> 7, hd = kc & 127;
    long o = ((long)(b * HKV_ + hk) * S_ + s) * HD_ + hd;
    *reinterpret_cast<unsigned*>(kb + o) =
        (unsigned)f2bf(y0) | ((unsigned)f2bf(y1) << 16);
  }
}

// ---------------- V transpose: qkv_b v-cols -> vt[b][kvh][hd][S] ----------------
__global__ void v_transpose(const unsigned short* __restrict__ qkv,
                            unsigned short* __restrict__ vt) {
  __shared__ unsigned short Lt[128 * 66];
  const int tid = threadIdx.x;
  const int s0 = blockIdx.x * 64;
  const int h = blockIdx.y;
  const int b = blockIdx.z;
#pragma unroll
  for (int c = tid; c < 1024; c += 256) {   // 64 tokens x 16 chunks
    int r = c >> 4, ch = c & 15;
    u16x8 v = *reinterpret_cast<const u16x8*>(
        qkv + (long)(b * S_ + s0 + r) * NQKV + 5120 + h * HD_ + ch * 8);
#pragma unroll
    for (int j = 0; j < 8; ++j) Lt[(ch * 8 + j) * 66 + r] = v[j];
  }
  __syncthreads();
#pragma unroll
  for (int c = tid; c < 1024; c += 256) {   // 128 hd-rows x 8 chunks
    int hd = c >> 3, ch = c & 7;
    u16x8 o;
#pragma unroll
    for (int j = 0; j < 8; ++j) o[j] = Lt[hd * 66 + ch * 8 + j];
    *reinterpret_cast<u16x8*>(
        vt + ((long)((b * HKV_ + h) * HD_ + hd)) * S_ + s0 + ch * 8) = o;
  }
}

// ---------------- Flash attention (non-causal, T=2048) ----------------
// Grid (S/128, HQ, B), 256 threads = 4 waves x 32 q-rows.
// K/Vt tiles staged via async16 with XOR chunk swizzle: phys = log ^ (row&7).
__global__ __launch_bounds__(256) void attn(
    const unsigned short* __restrict__ qb, const unsigned short* __restrict__ kb,
    const unsigned short* __restrict__ vt, unsigned short* __restrict__ ob) {
  __shared__ unsigned short Ks[64 * 128];   // [key][hd], swizzled chunks
  __shared__ unsigned short Vs[128 * 64];   // [hd][key], swizzled chunks
  __shared__ unsigned short Ps[4][32 * 72]; // per-wave P, padded stride 72
  const int tid = threadIdx.x;
  const int lane = tid & 63;
  const int wave = tid >> 6;
  const int quad = lane >> 4;
  const int l16 = lane & 15;
  const int qt = blockIdx.x;
  const int h = blockIdx.y;
  const int b = blockIdx.z;
  const int kvh = h >> 2;   // REPEAT = 4
  const unsigned short* qhead = qb + (long)(b * HQ_ + h) * S_ * HD_;
  const unsigned short* khead = kb + (long)(b * HKV_ + kvh) * S_ * HD_;
  const unsigned short* vthead = vt + (long)(b * HKV_ + kvh) * HD_ * S_;
  const int qbase = qt * 128 + wave * 32;

  // K staging: group g (0..15) = key rows g*4..g*4+3 (512 shorts).
  //   lane -> row g*4 + (lane>>4), phys chunk = lane&15,
  //   fetch logical = phys ^ (row&7); row&7 = (g&1)*4 + (lane>>4)  [g-dependent!]
  const int krow_in = lane >> 4;
  // V staging: group g = hd rows g*8..g*8+7; lane -> row g*8+(lane>>3),
  //   phys chunk = lane&7, fetch logical = phys ^ (row&7); row&7 = lane>>3
  const int vrow_in = lane >> 3;
  const int vlog = (lane & 7) ^ vrow_in;

  // Q A-fragments in registers for the whole kernel (q pre-scaled)
  bf16x8 qf[2][4];
#pragma unroll
  for (int mt = 0; mt < 2; ++mt)
#pragma unroll
    for (int kk = 0; kk < 4; ++kk)
      qf[mt][kk] = *reinterpret_cast<const bf16x8*>(
          qhead + (long)(qbase + mt * 16 + l16) * HD_ + kk * 32 + quad * 8);

  f32x4 O[2][8] = {};
  float m_st[2][4], l_st[2][4];
#pragma unroll
  for (int mt = 0; mt < 2; ++mt)
#pragma unroll
    for (int r = 0; r < 4; ++r) { m_st[mt][r] = -INFINITY; l_st[mt][r] = 0.f; }

  for (int t0 = 0; t0 < S_; t0 += 64) {
    __syncthreads();  // previous tile's readers done
#pragma unroll
    for (int j = 0; j < 4; ++j) {
      int g = wave * 4 + j;
      int kr7 = (g & 1) * 4 + krow_in;           // key row & 7
      int klog = (lane & 15) ^ kr7;
      async16(khead + (long)(t0 + g * 4 + krow_in) * HD_ + klog * 8,
              (void*)(Ks + g * 512));
      async16(vthead + (long)(g * 8 + vrow_in) * S_ + t0 + vlog * 8,
              (void*)(Vs + g * 512));
    }
    __syncthreads();  // vmcnt(0) drained before barrier -> tiles visible

    // S = Q K^T (softmax scale pre-folded into Q)
    f32x4 sc[2][4] = {};
#pragma unroll
    for (int nt = 0; nt < 4; ++nt) {
      const unsigned short* kr = Ks + (nt * 16 + l16) * 128;
#pragma unroll
      for (int kk = 0; kk < 4; ++kk) {
        int cc = (kk * 4 + quad) ^ (l16 & 7);
        bf16x8 bk = *reinterpret_cast<const bf16x8*>(kr + cc * 8);
        sc[0][nt] = __builtin_amdgcn_mfma_f32_16x16x32_bf16(qf[0][kk], bk, sc[0][nt], 0, 0, 0);
        sc[1][nt] = __builtin_amdgcn_mfma_f32_16x16x32_bf16(qf[1][kk], bk, sc[1][nt], 0, 0, 0);
      }
    }

    // online softmax per row (row = quad*4+r, cols spread over 16 lanes = DPP row)
#pragma unroll
    for (int mt = 0; mt < 2; ++mt) {
#pragma unroll
      for (int r = 0; r < 4; ++r) {
        float mx = fmaxf(fmaxf(sc[mt][0][r], sc[mt][1][r]),
                         fmaxf(sc[mt][2][r], sc[mt][3][r]));
        mx = row_max16(mx);
        float mnew = fmaxf(m_st[mt][r], mx);
        float al = __expf(m_st[mt][r] - mnew);  // first tile: exp(-inf)=0
        m_st[mt][r] = mnew;
        float rs = 0.f;
#pragma unroll
        for (int nt = 0; nt < 4; ++nt) {
          float p = __expf(sc[mt][nt][r] - mnew);
          sc[mt][nt][r] = p;
          rs += p;
        }
        rs = row_sum16(rs);
        l_st[mt][r] = l_st[mt][r] * al + rs;
#pragma unroll
        for (int n = 0; n < 8; ++n) O[mt][n][r] *= al;
      }
    }

    // P: C-layout regs -> per-wave LDS (same-wave RAW, in-order DS pipe)
    unsigned short* pw = Ps[wave];
#pragma unroll
    for (int mt = 0; mt < 2; ++mt)
#pragma unroll
      for (int nt = 0; nt < 4; ++nt)
#pragma unroll
        for (int r = 0; r < 4; ++r)
          pw[(mt * 16 + quad * 4 + r) * 72 + nt * 16 + l16] = f2bf(sc[mt][nt][r]);

    // O += P V
#pragma unroll
    for (int kt = 0; kt < 2; ++kt) {
      bf16x8 ap0 = *reinterpret_cast<const bf16x8*>(pw + l16 * 72 + kt * 32 + quad * 8);
      bf16x8 ap1 = *reinterpret_cast<const bf16x8*>(pw + (16 + l16) * 72 + kt * 32 + quad * 8);
#pragma unroll
      for (int n = 0; n < 8; ++n) {
        int cc = (kt * 4 + quad) ^ (l16 & 7);
        bf16x8 bv = *reinterpret_cast<const bf16x8*>(Vs + (n * 16 + l16) * 64 + cc * 8);
        O[0][n] = __builtin_amdgcn_mfma_f32_16x16x32_bf16(ap0, bv, O[0][n], 0, 0, 0);
        O[1][n] = __builtin_amdgcn_mfma_f32_16x16x32_bf16(ap1, bv, O[1][n], 0, 0, 0);
      }
    }
  }

  // epilogue: normalize and write attn_b[token][h*128+hd] as bf16
#pragma unroll
  for (int mt = 0; mt < 2; ++mt) {
    float rl[4];
#pragma unroll
    for (int r = 0; r < 4; ++r) rl[r] = 1.f / l_st[mt][r];
#pragma unroll
    for (int n = 0; n < 8; ++n)
#pragma unroll
      for (int r = 0; r < 4; ++r) {
        int srow = qbase + mt * 16 + quad * 4 + r;
        long o = ((long)(b * S_ + srow)) * 4096 + h * HD_ + n * 16 + l16;
        ob[o] = f2bf(O[mt][n][r] * rl[r]);
      }
  }
}

extern "C" void kernel_launch(void* const* d_in, const int* in_sizes, int n_in,
                              void* d_out, int out_size, void* d_ws, size_t ws_size,
                              hipStream_t stream) {
  const float* x  = (const float*)d_in[0];
  const float* wq = (const float*)d_in[1];
  const float* wk = (const float*)d_in[2];
  const float* wv = (const float*)d_in[3];
  const float* wo = (const float*)d_in[4];
  const float* fc = (const float*)d_in[5];
  const float* fs = (const float*)d_in[6];
  // d_in[7..9]: cache_k/cache_v (zeros) and start_pos (0) — attention covers
  // the full cache [0,2048) so the cache contents are exactly k,v.

  char* ws = (char*)d_ws;
  unsigned short* x_b    = (unsigned short*)(ws);                 // 33.5 MB
  unsigned short* wqkv_b = (unsigned short*)(ws + 33554432);      // 50.3 MB
  unsigned short* qkv_b  = (unsigned short*)(ws + 83886080);      // 50.3 MB (bf16)
  unsigned short* q_b    = (unsigned short*)(ws + 134217728);     // 33.5 MB
  unsigned short* k_b    = (unsigned short*)(ws + 167772160);     // 8.4 MB
  unsigned short* vt_b   = (unsigned short*)(ws + 176160768);     // 8.4 MB -> 184.5 MB
  unsigned short* wo_b   = x_b;                       // reuse: x_b dead after gemm1
  unsigned short* attn_b = qkv_b;                     // reuse: qkv_b dead after v_transpose
  float* out = (float*)d_out;

  cvt_bf16<<<2048, 256, 0, stream>>>(x, x_b, 4096 * 4096);
  cvt_bf16<<<2048, 256, 0, stream>>>(wq, wqkv_b, 4096 * 4096);
  cvt_bf16<<<512, 256, 0, stream>>>(wk, wqkv_b + 4096 * 4096, 1024 * 4096);
  cvt_bf16<<<512, 256, 0, stream>>>(wv, wqkv_b + 5120 * 4096, 1024 * 4096);
  gemm_bt<unsigned short><<<dim3(32, 48), 256, 0, stream>>>(x_b, wqkv_b, qkv_b, 4096, 6144, 4096);
  cvt_bf16<<<2048, 256, 0, stream>>>(wo, wo_b, 4096 * 4096);  // after gemm1 (aliases x_b)
  rope_pack<<<40960, 256, 0, stream>>>(qkv_b, fc, fs, q_b, k_b);
  v_transpose<<<dim3(32, 8, 2), 256, 0, stream>>>(qkv_b, vt_b);
  attn<<<dim3(16, 32, 2), 256, 0, stream>>>(q_b, k_b, vt_b, attn_b);
  gemm_bt<float><<<dim3(32, 32), 256, 0, stream>>>(attn_b, wo_b, out, 4096, 4096, 4096);
}